// Round 13
// baseline (186.681 us; speedup 1.0000x reference)
//
#include <hip/hip_runtime.h>
#include <hip/hip_bf16.h>
#include <stdint.h>

#define B_ROWS 16384
#define NVARS 64
#define LAG 16
#define H1 64
#define H2 1024
#define KDIM (NVARS * H1)   // 4096

typedef __attribute__((ext_vector_type(8))) short short8;
typedef __attribute__((ext_vector_type(4))) short short4v;
typedef __attribute__((ext_vector_type(4))) float f32x4;

typedef __attribute__((address_space(3))) uint8_t lds_u8;
typedef const __attribute__((address_space(1))) uint8_t glob_u8;

__device__ __forceinline__ void gload_lds16(const void* g, void* l) {
    __builtin_amdgcn_global_load_lds((glob_u8*)g, (lds_u8*)l, 16, 0, 0);
}

__device__ __forceinline__ short f2bf_s(float x) {
    __hip_bfloat16 h = __float2bfloat16(x);
    return *(short*)&h;
}
__device__ __forceinline__ float bf_s2f(short s) {
    __hip_bfloat16 h = *(__hip_bfloat16*)&s;
    return __bfloat162float(h);
}

// ---------------------------------------------------------------------------
// Kernel 1: per-var W1/W2 -> hi/lo B-operand prep (64 blocks, global writes)
// ---------------------------------------------------------------------------
__global__ __launch_bounds__(256) void prep_w12_kernel(
    const float* __restrict__ W1, const float* __restrict__ W2,
    short* __restrict__ w1bh, short* __restrict__ w1bl,
    short* __restrict__ w2bh, short* __restrict__ w2bl) {
    const int v = blockIdx.x, t = threadIdx.x;
    for (int idx = t; idx < 64 * 32; idx += 256) {
        int col = idx >> 5, k = idx & 31;
        float wv = W1[((size_t)v * LAG + (k & 15)) * H1 + col];
        short hi = f2bf_s(wv);
        w1bh[((size_t)v * 64 + col) * 40 + k] = hi;
        w1bl[((size_t)v * 64 + col) * 40 + k] = (k < 16) ? f2bf_s(wv - bf_s2f(hi)) : (short)0;
    }
    for (int idx = t; idx < 64 * 64; idx += 256) {
        int col = idx >> 6, k = idx & 63;
        float wv = W2[((size_t)v * H1 + k) * H1 + col];
        short hi = f2bf_s(wv);
        w2bh[((size_t)v * 64 + col) * 72 + k] = hi;
        w2bl[((size_t)v * 64 + col) * 72 + k] = f2bf_s(wv - bf_s2f(hi));
    }
}

// ---------------------------------------------------------------------------
// Kernel 2 (fused): [0,1024) W3 transpose->bf16 | [1024,1088) out=b4 |
//                   [1088,9280) subnets (r8-validated body, untouched)
// ---------------------------------------------------------------------------
__global__ __launch_bounds__(256) void subnets_fused_kernel(
    const float* __restrict__ inputs, const float* __restrict__ b1g,
    const float* __restrict__ b2g, const float* __restrict__ impg,
    const short* __restrict__ w1bh_g, const short* __restrict__ w1bl_g,
    const short* __restrict__ w2bh_g, const short* __restrict__ w2bl_g,
    const float* __restrict__ w3, const float* __restrict__ b4,
    __hip_bfloat16* __restrict__ w3t, float* __restrict__ out,
    __hip_bfloat16* __restrict__ agg) {
    __shared__ __align__(16) char smem[38912];
    const int bid = blockIdx.x;
    const int t = threadIdx.x;

    if (bid < 1024) {
        float (*tile)[65] = (float (*)[65])smem;
        const int k0 = (bid >> 4) * 64;
        const int n0 = (bid & 15) * 64;
        const int c = t & 63, r0 = t >> 6;
#pragma unroll
        for (int i = 0; i < 16; i++) {
            int r = r0 + i * 4;
            tile[r][c] = w3[(size_t)(k0 + r) * H2 + n0 + c];
        }
        __syncthreads();
#pragma unroll
        for (int i = 0; i < 16; i++) {
            int nr = r0 + i * 4;
            w3t[(size_t)(n0 + nr) * KDIM + k0 + c] = __float2bfloat16(tile[c][nr]);
        }
        return;
    }
    if (bid < 1088) {
        out[(bid - 1024) * 256 + t] = b4[0];
        return;
    }

    const int sbid = bid - 1088;
    const int v = sbid >> 7;
    const int b0 = (sbid & 127) * 128;
    const int lane = t & 63, wv = t >> 6;
    const int l15 = lane & 15, g = lane >> 4;

    short* xsS   = (short*)smem;
    short* w1bhS = (short*)(smem + 10240);
    short* w1blS = (short*)(smem + 15360);
    short* Hs    = (short*)smem;
    short* w2bhS = (short*)(smem + 20480);
    short* w2blS = (short*)(smem + 29696);

    for (int c = t; c < 320; c += 256) {
        gload_lds16(w1bh_g + (size_t)v * 2560 + c * 8, (char*)w1bhS + c * 16);
        gload_lds16(w1bl_g + (size_t)v * 2560 + c * 8, (char*)w1blS + c * 16);
    }
    for (int c = t; c < 576; c += 256) {
        gload_lds16(w2bh_g + (size_t)v * 4608 + c * 8, (char*)w2bhS + c * 16);
        gload_lds16(w2bl_g + (size_t)v * 4608 + c * 8, (char*)w2blS + c * 16);
    }
#pragma unroll
    for (int i = 0; i < 2; i++) {
        int idx = t + i * 256;
        int row = idx >> 2, seg = idx & 3;
        float4 x4 = *(const float4*)(inputs + (size_t)(b0 + row) * (NVARS * LAG) + v * LAG + seg * 4);
        const float* xp = (const float*)&x4;
        short4v hv, lv;
#pragma unroll
        for (int j = 0; j < 4; j++) {
            short hi = f2bf_s(xp[j]);
            hv[j] = hi;
            lv[j] = f2bf_s(xp[j] - bf_s2f(hi));
        }
        *(short4v*)&xsS[row * 40 + seg * 4] = hv;
        *(short4v*)&xsS[row * 40 + 16 + seg * 4] = lv;
    }
    __syncthreads();

    short8 a1[2], b1hF[4], b1lF[4];
#pragma unroll
    for (int mt = 0; mt < 2; mt++)
        a1[mt] = *(const short8*)&xsS[(wv * 32 + mt * 16 + l15) * 40 + g * 8];
#pragma unroll
    for (int nt = 0; nt < 4; nt++) {
        b1hF[nt] = *(const short8*)&w1bhS[(nt * 16 + l15) * 40 + g * 8];
        b1lF[nt] = *(const short8*)&w1blS[(nt * 16 + l15) * 40 + g * 8];
    }
    f32x4 acc1[2][4];
#pragma unroll
    for (int mt = 0; mt < 2; mt++)
#pragma unroll
        for (int nt = 0; nt < 4; nt++) {
            acc1[mt][nt] = (f32x4){0.f, 0.f, 0.f, 0.f};
            acc1[mt][nt] = __builtin_amdgcn_mfma_f32_16x16x32_bf16(a1[mt], b1hF[nt], acc1[mt][nt], 0, 0, 0);
            acc1[mt][nt] = __builtin_amdgcn_mfma_f32_16x16x32_bf16(a1[mt], b1lF[nt], acc1[mt][nt], 0, 0, 0);
        }
    __syncthreads();

#pragma unroll
    for (int mt = 0; mt < 2; mt++)
#pragma unroll
        for (int nt = 0; nt < 4; nt++) {
            int col = nt * 16 + l15;
            float bias = b1g[v * H1 + col];
#pragma unroll
            for (int r = 0; r < 4; r++) {
                float h = fmaxf(acc1[mt][nt][r] + bias, 0.f);
                int row = wv * 32 + mt * 16 + g * 4 + r;
                Hs[row * 72 + col] = f2bf_s(h);
            }
        }
    __syncthreads();

    short8 a2[2][2], b2hF[4][2], b2lF[4][2];
#pragma unroll
    for (int mt = 0; mt < 2; mt++)
#pragma unroll
        for (int kc = 0; kc < 2; kc++)
            a2[mt][kc] = *(const short8*)&Hs[(wv * 32 + mt * 16 + l15) * 72 + kc * 32 + g * 8];
#pragma unroll
    for (int nt = 0; nt < 4; nt++)
#pragma unroll
        for (int kc = 0; kc < 2; kc++) {
            b2hF[nt][kc] = *(const short8*)&w2bhS[(nt * 16 + l15) * 72 + kc * 32 + g * 8];
            b2lF[nt][kc] = *(const short8*)&w2blS[(nt * 16 + l15) * 72 + kc * 32 + g * 8];
        }
    f32x4 acc2[2][4];
#pragma unroll
    for (int mt = 0; mt < 2; mt++)
#pragma unroll
        for (int nt = 0; nt < 4; nt++) {
            f32x4 a = (f32x4){0.f, 0.f, 0.f, 0.f};
            a = __builtin_amdgcn_mfma_f32_16x16x32_bf16(a2[mt][0], b2hF[nt][0], a, 0, 0, 0);
            a = __builtin_amdgcn_mfma_f32_16x16x32_bf16(a2[mt][1], b2hF[nt][1], a, 0, 0, 0);
            a = __builtin_amdgcn_mfma_f32_16x16x32_bf16(a2[mt][0], b2lF[nt][0], a, 0, 0, 0);
            a = __builtin_amdgcn_mfma_f32_16x16x32_bf16(a2[mt][1], b2lF[nt][1], a, 0, 0, 0);
            acc2[mt][nt] = a;
        }

    const float impv = impg[v];
#pragma unroll
    for (int mt = 0; mt < 2; mt++)
#pragma unroll
        for (int nt = 0; nt < 4; nt++) {
            int col = nt * 16 + l15;
            float bias = b2g[v * H1 + col];
#pragma unroll
            for (int r = 0; r < 4; r++) {
                float o = fmaxf(acc2[mt][nt][r] + bias, 0.f) * impv;
                int row = b0 + wv * 32 + mt * 16 + g * 4 + r;
                agg[(size_t)row * KDIM + v * H1 + col] = __float2bfloat16(o);
            }
        }
}

// ---------------------------------------------------------------------------
// Kernel 3: relu(agg @ W3 + b3) . W4 -> atomicAdd into out.
// r13: TLP-optimized. BM=128 x BN=256 tile -> grid 512 = 2 blocks/CU
// (16 waves/CU, 4/SIMD): independent blocks decouple barrier stalls.
// 8 waves (2M x 4N), wave tile 64x64, acc[4][4] (64 VGPR). 3-deep buffer
// rotation of 24-KB pairs (A 8 KB + B 16 KB), 72 KB/block LDS.
// Per tile tt: { stage tt+2 into buf (tt+2)%3 (3 gloads/thr) | 8 ds_reads
// from buf tt%3 | 16 MFMA (setprio) | vmcnt(3) certifies tt+1 | barrier }.
// Flight for a stage = ~2 tiles >> 900-cyc HBM latency.
// __launch_bounds__(512,4): 128-VGPR cap (acc 64 + frags 32 + addr ~ 120).
// ---------------------------------------------------------------------------
#define NT 128   // K-tiles of 32

__global__ __launch_bounds__(512, 4) void gemm3_kernel(
    const __hip_bfloat16* __restrict__ agg,   // [16384][4096]
    const __hip_bfloat16* __restrict__ w3t,   // [1024][4096]
    const float* __restrict__ b3, const float* __restrict__ W4,
    float* __restrict__ out) {
    // T1 bijective XCD swizzle: nwg=512, 512%8==0; XCD x owns 64 consecutive
    // swizzled bids = 16 row-panels x 4 col-tiles (A/B panel L2 locality).
    const int bid = ((blockIdx.x & 7) << 6) + (blockIdx.x >> 3);
    const int brow = (bid >> 2) * 128;
    const int bcol = (bid & 3) * 256;
    const int t = threadIdx.x;
    const int lane = t & 63;
    const int wid = t >> 6;                   // 8 waves
    const int wm = wid >> 2, wn = wid & 3;    // 2 x 4, wave tile 64x64
    const int l15 = lane & 15, g = lane >> 4;

    // LDS: 3 buffers of 24 KB: A [128][32] @ +0 (8 KB), B [256][32] @ +8192
    __shared__ __align__(16) char smem[73728];

    // staging (512 thr): A = 1 chunk/thr (512 x 16B), B = 2 chunks/thr.
    // dest linear, source col pre-swizzled (st_16x32, r8-proven).
    const int rA = t >> 2;
    const int colA = ((t & 3) * 8) ^ ((rA & 8) ? 16 : 0);
    const int cB0 = t, cB1 = t + 512;
    const int rB0 = cB0 >> 2, rB1 = cB1 >> 2;
    const int colB0 = ((cB0 & 3) * 8) ^ ((rB0 & 8) ? 16 : 0);
    const int colB1 = ((cB1 & 3) * 8) ^ ((rB1 & 8) ? 16 : 0);
    const __hip_bfloat16* aS = agg + (size_t)(brow + rA) * KDIM + colA;
    const __hip_bfloat16* bS0 = w3t + (size_t)(bcol + rB0) * KDIM + colB0;
    const __hip_bfloat16* bS1 = w3t + (size_t)(bcol + rB1) * KDIM + colB1;

#define STAGE(p, kt) do { \
        gload_lds16(aS + (size_t)(kt) * 32,  smem + (p) * 24576 + t * 16); \
        gload_lds16(bS0 + (size_t)(kt) * 32, smem + (p) * 24576 + 8192 + cB0 * 16); \
        gload_lds16(bS1 + (size_t)(kt) * 32, smem + (p) * 24576 + 8192 + cB1 * 16); } while (0)

    // swizzled fragment reads (row&8 == l15&8 for all m/n)
    const int coff = (g * 16) ^ ((l15 & 8) ? 32 : 0);
    const int aBase = (wm * 64 + l15) * 64 + coff;
    const int bBase = 8192 + (wn * 64 + l15) * 64 + coff;

#define LDFRAGS(p) do { \
        fa[0] = *(const short8*)(smem + (p) * 24576 + aBase + 0 * 1024); \
        fa[1] = *(const short8*)(smem + (p) * 24576 + aBase + 1 * 1024); \
        fa[2] = *(const short8*)(smem + (p) * 24576 + aBase + 2 * 1024); \
        fa[3] = *(const short8*)(smem + (p) * 24576 + aBase + 3 * 1024); \
        fb[0] = *(const short8*)(smem + (p) * 24576 + bBase + 0 * 1024); \
        fb[1] = *(const short8*)(smem + (p) * 24576 + bBase + 1 * 1024); \
        fb[2] = *(const short8*)(smem + (p) * 24576 + bBase + 2 * 1024); \
        fb[3] = *(const short8*)(smem + (p) * 24576 + bBase + 3 * 1024); } while (0)

#define MM() do { \
        __builtin_amdgcn_s_setprio(1); \
        _Pragma("unroll") \
        for (int mm = 0; mm < 4; mm++) \
            _Pragma("unroll") \
            for (int nn = 0; nn < 4; nn++) \
                acc[mm][nn] = __builtin_amdgcn_mfma_f32_16x16x32_bf16( \
                    fa[mm], fb[nn], acc[mm][nn], 0, 0, 0); \
        __builtin_amdgcn_s_setprio(0); } while (0)

#define TILE(p, DOSTAGE, ps, kts, VMSTR) do { \
        if (DOSTAGE) STAGE(ps, kts); \
        LDFRAGS(p); \
        MM(); \
        asm volatile(VMSTR ::: "memory"); \
        __builtin_amdgcn_s_barrier(); \
        __builtin_amdgcn_sched_barrier(0); } while (0)

    short8 fa[4], fb[4];
    f32x4 acc[4][4];
#pragma unroll
    for (int m = 0; m < 4; m++)
#pragma unroll
        for (int n = 0; n < 4; n++) acc[m][n] = (f32x4){0.f, 0.f, 0.f, 0.f};

    // prologue: stage tiles 0,1 (6 gloads/thr); vmcnt(3) certifies tile0.
    STAGE(0, 0);
    STAGE(1, 1);
    asm volatile("s_waitcnt vmcnt(3)" ::: "memory");
    __builtin_amdgcn_s_barrier();
    __builtin_amdgcn_sched_barrier(0);

    // main loop: 42 iters x 3 tiles = tiles 0..125, staging tiles 2..127.
    // Ledger: end of tile tt outstanding = [tt+1:3, tt+2:3] -> vmcnt(3).
    for (int i = 0; i < 42; ++i) {
        const int tt = i * 3;
        TILE(0, 1, 2, tt + 2, "s_waitcnt vmcnt(3)");
        TILE(1, 1, 0, tt + 3, "s_waitcnt vmcnt(3)");
        TILE(2, 1, 1, tt + 4, "s_waitcnt vmcnt(3)");
    }
    // tail: tile 126 (p=0, drain all), tile 127 (p=1)
    TILE(0, 0, 0, 0, "s_waitcnt vmcnt(0)");
    LDFRAGS(1);
    MM();

    // epilogue: bias+relu, dot W4, 16-lane reduce, atomicAdd per row
    float bias[4], w4v[4];
#pragma unroll
    for (int n = 0; n < 4; n++) {
        int col = bcol + wn * 64 + n * 16 + l15;
        bias[n] = b3[col];
        w4v[n] = W4[col];
    }
#pragma unroll
    for (int m = 0; m < 4; m++) {
        float pr0 = 0.f, pr1 = 0.f, pr2 = 0.f, pr3 = 0.f;
#pragma unroll
        for (int n = 0; n < 4; n++) {
            pr0 += fmaxf(acc[m][n][0] + bias[n], 0.f) * w4v[n];
            pr1 += fmaxf(acc[m][n][1] + bias[n], 0.f) * w4v[n];
            pr2 += fmaxf(acc[m][n][2] + bias[n], 0.f) * w4v[n];
            pr3 += fmaxf(acc[m][n][3] + bias[n], 0.f) * w4v[n];
        }
#pragma unroll
        for (int mask = 1; mask < 16; mask <<= 1) {
            pr0 += __shfl_xor(pr0, mask, 64);
            pr1 += __shfl_xor(pr1, mask, 64);
            pr2 += __shfl_xor(pr2, mask, 64);
            pr3 += __shfl_xor(pr3, mask, 64);
        }
        if (l15 == 0) {
            int row = brow + wm * 64 + m * 16 + g * 4;
            atomicAdd(&out[row + 0], pr0);
            atomicAdd(&out[row + 1], pr1);
            atomicAdd(&out[row + 2], pr2);
            atomicAdd(&out[row + 3], pr3);
        }
    }
}

// ---------------------------------------------------------------------------
extern "C" void kernel_launch(void* const* d_in, const int* in_sizes, int n_in,
                              void* d_out, int out_size, void* d_ws, size_t ws_size,
                              hipStream_t stream) {
    const float* inputs = (const float*)d_in[0];
    const float* W1 = (const float*)d_in[1];
    const float* b1 = (const float*)d_in[2];
    const float* W2 = (const float*)d_in[3];
    const float* b2 = (const float*)d_in[4];
    const float* imp = (const float*)d_in[5];
    const float* W3 = (const float*)d_in[6];
    const float* b3 = (const float*)d_in[7];
    const float* W4 = (const float*)d_in[8];
    const float* b4 = (const float*)d_in[9];
    float* out = (float*)d_out;

    char* ws = (char*)d_ws;
    const size_t agg_bytes = (size_t)B_ROWS * KDIM * 2;        // 134 MB
    const size_t w3t_bytes = (size_t)H2 * KDIM * 2;            // 8.4 MB
    const size_t w1b_bytes = (size_t)NVARS * 64 * 40 * 2;
    const size_t w2b_bytes = (size_t)NVARS * 64 * 72 * 2;

    __hip_bfloat16* agg = (__hip_bfloat16*)ws;
    __hip_bfloat16* w3t = (__hip_bfloat16*)(ws + agg_bytes);
    short* w1bh = (short*)(ws + agg_bytes + w3t_bytes);
    short* w1bl = (short*)(ws + agg_bytes + w3t_bytes + w1b_bytes);
    short* w2bh = (short*)(ws + agg_bytes + w3t_bytes + 2 * w1b_bytes);
    short* w2bl = (short*)(ws + agg_bytes + w3t_bytes + 2 * w1b_bytes + w2b_bytes);

    hipLaunchKernelGGL(prep_w12_kernel, dim3(NVARS), dim3(256), 0, stream,
                       W1, W2, w1bh, w1bl, w2bh, w2bl);
    hipLaunchKernelGGL(subnets_fused_kernel, dim3(1088 + NVARS * (B_ROWS / 128)), dim3(256), 0, stream,
                       inputs, b1, b2, imp, w1bh, w1bl, w2bh, w2bl,
                       W3, b4, w3t, out, agg);
    hipLaunchKernelGGL(gemm3_kernel, dim3((B_ROWS / 128) * (H2 / 256)), dim3(512), 0, stream,
                       agg, w3t, b3, W4, out);
}

// Round 14
// 166.106 us; speedup vs baseline: 1.1239x; 1.1239x over previous
//
#include <hip/hip_runtime.h>
#include <hip/hip_bf16.h>
#include <stdint.h>

#define B_ROWS 16384
#define NVARS 64
#define LAG 16
#define H1 64
#define H2 1024
#define KDIM (NVARS * H1)   // 4096

typedef __attribute__((ext_vector_type(8))) short short8;
typedef __attribute__((ext_vector_type(4))) short short4v;
typedef __attribute__((ext_vector_type(4))) float f32x4;

typedef __attribute__((address_space(3))) uint8_t lds_u8;
typedef const __attribute__((address_space(1))) uint8_t glob_u8;

__device__ __forceinline__ void gload_lds16(const void* g, void* l) {
    __builtin_amdgcn_global_load_lds((glob_u8*)g, (lds_u8*)l, 16, 0, 0);
}

__device__ __forceinline__ short f2bf_s(float x) {
    __hip_bfloat16 h = __float2bfloat16(x);
    return *(short*)&h;
}
__device__ __forceinline__ float bf_s2f(short s) {
    __hip_bfloat16 h = *(__hip_bfloat16*)&s;
    return __bfloat162float(h);
}

// ---------------------------------------------------------------------------
// Kernel 1: per-var W1/W2 -> hi/lo B-operand prep (64 blocks, global writes)
// ---------------------------------------------------------------------------
__global__ __launch_bounds__(256) void prep_w12_kernel(
    const float* __restrict__ W1, const float* __restrict__ W2,
    short* __restrict__ w1bh, short* __restrict__ w1bl,
    short* __restrict__ w2bh, short* __restrict__ w2bl) {
    const int v = blockIdx.x, t = threadIdx.x;
    for (int idx = t; idx < 64 * 32; idx += 256) {
        int col = idx >> 5, k = idx & 31;
        float wv = W1[((size_t)v * LAG + (k & 15)) * H1 + col];
        short hi = f2bf_s(wv);
        w1bh[((size_t)v * 64 + col) * 40 + k] = hi;
        w1bl[((size_t)v * 64 + col) * 40 + k] = (k < 16) ? f2bf_s(wv - bf_s2f(hi)) : (short)0;
    }
    for (int idx = t; idx < 64 * 64; idx += 256) {
        int col = idx >> 6, k = idx & 63;
        float wv = W2[((size_t)v * H1 + k) * H1 + col];
        short hi = f2bf_s(wv);
        w2bh[((size_t)v * 64 + col) * 72 + k] = hi;
        w2bl[((size_t)v * 64 + col) * 72 + k] = f2bf_s(wv - bf_s2f(hi));
    }
}

// ---------------------------------------------------------------------------
// Kernel 2 (fused): [0,1024) W3 transpose->bf16 | [1024,1088) out=b4 |
//                   [1088,9280) subnets (r8-validated body, untouched)
// ---------------------------------------------------------------------------
__global__ __launch_bounds__(256) void subnets_fused_kernel(
    const float* __restrict__ inputs, const float* __restrict__ b1g,
    const float* __restrict__ b2g, const float* __restrict__ impg,
    const short* __restrict__ w1bh_g, const short* __restrict__ w1bl_g,
    const short* __restrict__ w2bh_g, const short* __restrict__ w2bl_g,
    const float* __restrict__ w3, const float* __restrict__ b4,
    __hip_bfloat16* __restrict__ w3t, float* __restrict__ out,
    __hip_bfloat16* __restrict__ agg) {
    __shared__ __align__(16) char smem[38912];
    const int bid = blockIdx.x;
    const int t = threadIdx.x;

    if (bid < 1024) {
        float (*tile)[65] = (float (*)[65])smem;
        const int k0 = (bid >> 4) * 64;
        const int n0 = (bid & 15) * 64;
        const int c = t & 63, r0 = t >> 6;
#pragma unroll
        for (int i = 0; i < 16; i++) {
            int r = r0 + i * 4;
            tile[r][c] = w3[(size_t)(k0 + r) * H2 + n0 + c];
        }
        __syncthreads();
#pragma unroll
        for (int i = 0; i < 16; i++) {
            int nr = r0 + i * 4;
            w3t[(size_t)(n0 + nr) * KDIM + k0 + c] = __float2bfloat16(tile[c][nr]);
        }
        return;
    }
    if (bid < 1088) {
        out[(bid - 1024) * 256 + t] = b4[0];
        return;
    }

    const int sbid = bid - 1088;
    const int v = sbid >> 7;
    const int b0 = (sbid & 127) * 128;
    const int lane = t & 63, wv = t >> 6;
    const int l15 = lane & 15, g = lane >> 4;

    short* xsS   = (short*)smem;
    short* w1bhS = (short*)(smem + 10240);
    short* w1blS = (short*)(smem + 15360);
    short* Hs    = (short*)smem;
    short* w2bhS = (short*)(smem + 20480);
    short* w2blS = (short*)(smem + 29696);

    for (int c = t; c < 320; c += 256) {
        gload_lds16(w1bh_g + (size_t)v * 2560 + c * 8, (char*)w1bhS + c * 16);
        gload_lds16(w1bl_g + (size_t)v * 2560 + c * 8, (char*)w1blS + c * 16);
    }
    for (int c = t; c < 576; c += 256) {
        gload_lds16(w2bh_g + (size_t)v * 4608 + c * 8, (char*)w2bhS + c * 16);
        gload_lds16(w2bl_g + (size_t)v * 4608 + c * 8, (char*)w2blS + c * 16);
    }
#pragma unroll
    for (int i = 0; i < 2; i++) {
        int idx = t + i * 256;
        int row = idx >> 2, seg = idx & 3;
        float4 x4 = *(const float4*)(inputs + (size_t)(b0 + row) * (NVARS * LAG) + v * LAG + seg * 4);
        const float* xp = (const float*)&x4;
        short4v hv, lv;
#pragma unroll
        for (int j = 0; j < 4; j++) {
            short hi = f2bf_s(xp[j]);
            hv[j] = hi;
            lv[j] = f2bf_s(xp[j] - bf_s2f(hi));
        }
        *(short4v*)&xsS[row * 40 + seg * 4] = hv;
        *(short4v*)&xsS[row * 40 + 16 + seg * 4] = lv;
    }
    __syncthreads();

    short8 a1[2], b1hF[4], b1lF[4];
#pragma unroll
    for (int mt = 0; mt < 2; mt++)
        a1[mt] = *(const short8*)&xsS[(wv * 32 + mt * 16 + l15) * 40 + g * 8];
#pragma unroll
    for (int nt = 0; nt < 4; nt++) {
        b1hF[nt] = *(const short8*)&w1bhS[(nt * 16 + l15) * 40 + g * 8];
        b1lF[nt] = *(const short8*)&w1blS[(nt * 16 + l15) * 40 + g * 8];
    }
    f32x4 acc1[2][4];
#pragma unroll
    for (int mt = 0; mt < 2; mt++)
#pragma unroll
        for (int nt = 0; nt < 4; nt++) {
            acc1[mt][nt] = (f32x4){0.f, 0.f, 0.f, 0.f};
            acc1[mt][nt] = __builtin_amdgcn_mfma_f32_16x16x32_bf16(a1[mt], b1hF[nt], acc1[mt][nt], 0, 0, 0);
            acc1[mt][nt] = __builtin_amdgcn_mfma_f32_16x16x32_bf16(a1[mt], b1lF[nt], acc1[mt][nt], 0, 0, 0);
        }
    __syncthreads();

#pragma unroll
    for (int mt = 0; mt < 2; mt++)
#pragma unroll
        for (int nt = 0; nt < 4; nt++) {
            int col = nt * 16 + l15;
            float bias = b1g[v * H1 + col];
#pragma unroll
            for (int r = 0; r < 4; r++) {
                float h = fmaxf(acc1[mt][nt][r] + bias, 0.f);
                int row = wv * 32 + mt * 16 + g * 4 + r;
                Hs[row * 72 + col] = f2bf_s(h);
            }
        }
    __syncthreads();

    short8 a2[2][2], b2hF[4][2], b2lF[4][2];
#pragma unroll
    for (int mt = 0; mt < 2; mt++)
#pragma unroll
        for (int kc = 0; kc < 2; kc++)
            a2[mt][kc] = *(const short8*)&Hs[(wv * 32 + mt * 16 + l15) * 72 + kc * 32 + g * 8];
#pragma unroll
    for (int nt = 0; nt < 4; nt++)
#pragma unroll
        for (int kc = 0; kc < 2; kc++) {
            b2hF[nt][kc] = *(const short8*)&w2bhS[(nt * 16 + l15) * 72 + kc * 32 + g * 8];
            b2lF[nt][kc] = *(const short8*)&w2blS[(nt * 16 + l15) * 72 + kc * 32 + g * 8];
        }
    f32x4 acc2[2][4];
#pragma unroll
    for (int mt = 0; mt < 2; mt++)
#pragma unroll
        for (int nt = 0; nt < 4; nt++) {
            f32x4 a = (f32x4){0.f, 0.f, 0.f, 0.f};
            a = __builtin_amdgcn_mfma_f32_16x16x32_bf16(a2[mt][0], b2hF[nt][0], a, 0, 0, 0);
            a = __builtin_amdgcn_mfma_f32_16x16x32_bf16(a2[mt][1], b2hF[nt][1], a, 0, 0, 0);
            a = __builtin_amdgcn_mfma_f32_16x16x32_bf16(a2[mt][0], b2lF[nt][0], a, 0, 0, 0);
            a = __builtin_amdgcn_mfma_f32_16x16x32_bf16(a2[mt][1], b2lF[nt][1], a, 0, 0, 0);
            acc2[mt][nt] = a;
        }

    const float impv = impg[v];
#pragma unroll
    for (int mt = 0; mt < 2; mt++)
#pragma unroll
        for (int nt = 0; nt < 4; nt++) {
            int col = nt * 16 + l15;
            float bias = b2g[v * H1 + col];
#pragma unroll
            for (int r = 0; r < 4; r++) {
                float o = fmaxf(acc2[mt][nt][r] + bias, 0.f) * impv;
                int row = b0 + wv * 32 + mt * 16 + g * 4 + r;
                agg[(size_t)row * KDIM + v * H1 + col] = __float2bfloat16(o);
            }
        }
}

// ---------------------------------------------------------------------------
// Kernel 3: relu(agg @ W3 + b3) . W4 -> atomicAdd into out.
// r8-exact best-known schedule (110 us, MfmaUtil 55%): 256x256 tile, BK=32,
// 8 waves, 4 LDS buffer pairs, stage tt+3 during tt, 1 barrier + 1 vmcnt(8)
// per K-tile, st_16x32 swizzle, T1 XCD swizzle.
// ---------------------------------------------------------------------------
#define NT 128   // K-tiles of 32

__global__ __launch_bounds__(512, 2) void gemm3_kernel(
    const __hip_bfloat16* __restrict__ agg,   // [16384][4096]
    const __hip_bfloat16* __restrict__ w3t,   // [1024][4096]
    const float* __restrict__ b3, const float* __restrict__ W4,
    float* __restrict__ out) {
    const int bid = ((blockIdx.x & 7) << 5) + (blockIdx.x >> 3);
    const int brow = (bid >> 2) * 256;
    const int bcol = (bid & 3) * 256;
    const int t = threadIdx.x;
    const int lane = t & 63;
    const int wid = t >> 6;
    const int wm = wid >> 2, wn = wid & 3;
    const int l15 = lane & 15, g = lane >> 4;

    __shared__ __align__(16) char smem[131072];

    const int c0 = t, c1 = t + 512;
    const int r0 = c0 >> 2, r1 = c1 >> 2;
    const int col0 = ((c0 & 3) * 8) ^ ((r0 & 8) ? 16 : 0);
    const int col1 = ((c1 & 3) * 8) ^ ((r1 & 8) ? 16 : 0);
    const __hip_bfloat16* aS0 = agg + (size_t)(brow + r0) * KDIM + col0;
    const __hip_bfloat16* aS1 = agg + (size_t)(brow + r1) * KDIM + col1;
    const __hip_bfloat16* bS0 = w3t + (size_t)(bcol + r0) * KDIM + col0;
    const __hip_bfloat16* bS1 = w3t + (size_t)(bcol + r1) * KDIM + col1;

#define STAGE_A(p, kt) do { \
        gload_lds16(aS0 + (kt) * 32, smem + (p) * 32768 + c0 * 16); \
        gload_lds16(aS1 + (kt) * 32, smem + (p) * 32768 + c1 * 16); } while (0)
#define STAGE_B(p, kt) do { \
        gload_lds16(bS0 + (kt) * 32, smem + (p) * 32768 + 16384 + c0 * 16); \
        gload_lds16(bS1 + (kt) * 32, smem + (p) * 32768 + 16384 + c1 * 16); } while (0)

    const int coff = (g * 16) ^ ((l15 & 8) ? 32 : 0);
    const int aBase = (wm * 128 + l15) * 64 + coff;
    const int bBase = 16384 + (wn * 64 + l15) * 64 + coff;

#define LDA(i, p) fa[i] = *(const short8*)(smem + (p) * 32768 + aBase + (i) * 1024)
#define LDB(i, p) fb[i] = *(const short8*)(smem + (p) * 32768 + bBase + (i) * 1024)

    short8 fa[8], fb[4];
    f32x4 acc[8][4];
#pragma unroll
    for (int m = 0; m < 8; m++)
#pragma unroll
        for (int n = 0; n < 4; n++) acc[m][n] = (f32x4){0.f, 0.f, 0.f, 0.f};

    STAGE_A(0, 0); STAGE_B(0, 0);
    STAGE_A(1, 1); STAGE_B(1, 1);
    STAGE_A(2, 2); STAGE_B(2, 2);
    asm volatile("s_waitcnt vmcnt(8)" ::: "memory");
    __builtin_amdgcn_s_barrier();
    __builtin_amdgcn_sched_barrier(0);

#define PH_A(p, DOSTAGE, kt3) do { \
        LDA(0, p); LDA(1, p); LDA(2, p); LDA(3, p); \
        LDB(0, p); LDB(1, p); LDB(2, p); LDB(3, p); \
        if (DOSTAGE) STAGE_A((kt3) & 3, kt3); \
        __builtin_amdgcn_s_setprio(1); \
        _Pragma("unroll") \
        for (int mm = 0; mm < 4; mm++) \
            _Pragma("unroll") \
            for (int nn = 0; nn < 4; nn++) \
                acc[mm][nn] = __builtin_amdgcn_mfma_f32_16x16x32_bf16( \
                    fa[mm], fb[nn], acc[mm][nn], 0, 0, 0); \
        __builtin_amdgcn_s_setprio(0); } while (0)

#define PH_B(p, DOSTAGE, kt3, VMSTR) do { \
        LDA(4, p); LDA(5, p); LDA(6, p); LDA(7, p); \
        if (DOSTAGE) STAGE_B((kt3) & 3, kt3); \
        __builtin_amdgcn_s_setprio(1); \
        _Pragma("unroll") \
        for (int mm = 0; mm < 4; mm++) \
            _Pragma("unroll") \
            for (int nn = 0; nn < 4; nn++) \
                acc[4 + mm][nn] = __builtin_amdgcn_mfma_f32_16x16x32_bf16( \
                    fa[4 + mm], fb[nn], acc[4 + mm][nn], 0, 0, 0); \
        __builtin_amdgcn_s_setprio(0); \
        asm volatile(VMSTR ::: "memory"); \
        __builtin_amdgcn_s_barrier(); \
        __builtin_amdgcn_sched_barrier(0); } while (0)

#pragma unroll 4
    for (int tt = 0; tt < NT - 4; ++tt) {
        const int p = tt & 3;
        PH_A(p, 1, tt + 3);
        PH_B(p, 1, tt + 3, "s_waitcnt vmcnt(8)");
    }
    PH_A(0, 1, 127); PH_B(0, 1, 127, "s_waitcnt vmcnt(8)");
    PH_A(1, 0, 0);   PH_B(1, 0, 0, "s_waitcnt vmcnt(4)");
    PH_A(2, 0, 0);   PH_B(2, 0, 0, "s_waitcnt vmcnt(0)");
    PH_A(3, 0, 0);   PH_B(3, 0, 0, "s_waitcnt vmcnt(0)");

    float bias[4], w4v[4];
#pragma unroll
    for (int n = 0; n < 4; n++) {
        int col = bcol + wn * 64 + n * 16 + l15;
        bias[n] = b3[col];
        w4v[n] = W4[col];
    }
#pragma unroll
    for (int m = 0; m < 8; m++) {
        float pr0 = 0.f, pr1 = 0.f, pr2 = 0.f, pr3 = 0.f;
#pragma unroll
        for (int n = 0; n < 4; n++) {
            pr0 += fmaxf(acc[m][n][0] + bias[n], 0.f) * w4v[n];
            pr1 += fmaxf(acc[m][n][1] + bias[n], 0.f) * w4v[n];
            pr2 += fmaxf(acc[m][n][2] + bias[n], 0.f) * w4v[n];
            pr3 += fmaxf(acc[m][n][3] + bias[n], 0.f) * w4v[n];
        }
#pragma unroll
        for (int mask = 1; mask < 16; mask <<= 1) {
            pr0 += __shfl_xor(pr0, mask, 64);
            pr1 += __shfl_xor(pr1, mask, 64);
            pr2 += __shfl_xor(pr2, mask, 64);
            pr3 += __shfl_xor(pr3, mask, 64);
        }
        if (l15 == 0) {
            int row = brow + wm * 128 + m * 16 + g * 4;
            atomicAdd(&out[row + 0], pr0);
            atomicAdd(&out[row + 1], pr1);
            atomicAdd(&out[row + 2], pr2);
            atomicAdd(&out[row + 3], pr3);
        }
    }
}

// ---------------------------------------------------------------------------
extern "C" void kernel_launch(void* const* d_in, const int* in_sizes, int n_in,
                              void* d_out, int out_size, void* d_ws, size_t ws_size,
                              hipStream_t stream) {
    const float* inputs = (const float*)d_in[0];
    const float* W1 = (const float*)d_in[1];
    const float* b1 = (const float*)d_in[2];
    const float* W2 = (const float*)d_in[3];
    const float* b2 = (const float*)d_in[4];
    const float* imp = (const float*)d_in[5];
    const float* W3 = (const float*)d_in[6];
    const float* b3 = (const float*)d_in[7];
    const float* W4 = (const float*)d_in[8];
    const float* b4 = (const float*)d_in[9];
    float* out = (float*)d_out;

    char* ws = (char*)d_ws;
    const size_t agg_bytes = (size_t)B_ROWS * KDIM * 2;        // 134 MB
    const size_t w3t_bytes = (size_t)H2 * KDIM * 2;            // 8.4 MB
    const size_t w1b_bytes = (size_t)NVARS * 64 * 40 * 2;
    const size_t w2b_bytes = (size_t)NVARS * 64 * 72 * 2;

    __hip_bfloat16* agg = (__hip_bfloat16*)ws;
    __hip_bfloat16* w3t = (__hip_bfloat16*)(ws + agg_bytes);
    short* w1bh = (short*)(ws + agg_bytes + w3t_bytes);
    short* w1bl = (short*)(ws + agg_bytes + w3t_bytes + w1b_bytes);
    short* w2bh = (short*)(ws + agg_bytes + w3t_bytes + 2 * w1b_bytes);
    short* w2bl = (short*)(ws + agg_bytes + w3t_bytes + 2 * w1b_bytes + w2b_bytes);

    hipLaunchKernelGGL(prep_w12_kernel, dim3(NVARS), dim3(256), 0, stream,
                       W1, W2, w1bh, w1bl, w2bh, w2bl);
    hipLaunchKernelGGL(subnets_fused_kernel, dim3(1088 + NVARS * (B_ROWS / 128)), dim3(256), 0, stream,
                       inputs, b1, b2, imp, w1bh, w1bl, w2bh, w2bl,
                       W3, b4, w3t, out, agg);
    hipLaunchKernelGGL(gemm3_kernel, dim3((B_ROWS / 256) * (H2 / 256)), dim3(512), 0, stream,
                       agg, w3t, b3, W4, out);
}

// Round 15
// 166.029 us; speedup vs baseline: 1.1244x; 1.0005x over previous
//
#include <hip/hip_runtime.h>
#include <hip/hip_bf16.h>
#include <stdint.h>

#define B_ROWS 16384
#define NVARS 64
#define LAG 16
#define H1 64
#define H2 1024
#define KDIM (NVARS * H1)   // 4096

typedef __attribute__((ext_vector_type(8))) short short8;
typedef __attribute__((ext_vector_type(4))) short short4v;
typedef __attribute__((ext_vector_type(4))) float f32x4;

typedef __attribute__((address_space(3))) uint8_t lds_u8;
typedef const __attribute__((address_space(1))) uint8_t glob_u8;

__device__ __forceinline__ void gload_lds16(const void* g, void* l) {
    __builtin_amdgcn_global_load_lds((glob_u8*)g, (lds_u8*)l, 16, 0, 0);
}

__device__ __forceinline__ short f2bf_s(float x) {
    __hip_bfloat16 h = __float2bfloat16(x);
    return *(short*)&h;
}
__device__ __forceinline__ float bf_s2f(short s) {
    __hip_bfloat16 h = *(__hip_bfloat16*)&s;
    return __bfloat162float(h);
}

// ---------------------------------------------------------------------------
// Kernel 1: per-var W1/W2 -> hi/lo B-operand prep (64 blocks, global writes)
// ---------------------------------------------------------------------------
__global__ __launch_bounds__(256) void prep_w12_kernel(
    const float* __restrict__ W1, const float* __restrict__ W2,
    short* __restrict__ w1bh, short* __restrict__ w1bl,
    short* __restrict__ w2bh, short* __restrict__ w2bl) {
    const int v = blockIdx.x, t = threadIdx.x;
    for (int idx = t; idx < 64 * 32; idx += 256) {
        int col = idx >> 5, k = idx & 31;
        float wv = W1[((size_t)v * LAG + (k & 15)) * H1 + col];
        short hi = f2bf_s(wv);
        w1bh[((size_t)v * 64 + col) * 40 + k] = hi;
        w1bl[((size_t)v * 64 + col) * 40 + k] = (k < 16) ? f2bf_s(wv - bf_s2f(hi)) : (short)0;
    }
    for (int idx = t; idx < 64 * 64; idx += 256) {
        int col = idx >> 6, k = idx & 63;
        float wv = W2[((size_t)v * H1 + k) * H1 + col];
        short hi = f2bf_s(wv);
        w2bh[((size_t)v * 64 + col) * 72 + k] = hi;
        w2bl[((size_t)v * 64 + col) * 72 + k] = f2bf_s(wv - bf_s2f(hi));
    }
}

// ---------------------------------------------------------------------------
// Kernel 2 (fused): [0,1024) W3 transpose->bf16 | [1024,1088) out=b4 |
//                   [1088,9280) subnets (r8-validated body, untouched)
// ---------------------------------------------------------------------------
__global__ __launch_bounds__(256) void subnets_fused_kernel(
    const float* __restrict__ inputs, const float* __restrict__ b1g,
    const float* __restrict__ b2g, const float* __restrict__ impg,
    const short* __restrict__ w1bh_g, const short* __restrict__ w1bl_g,
    const short* __restrict__ w2bh_g, const short* __restrict__ w2bl_g,
    const float* __restrict__ w3, const float* __restrict__ b4,
    __hip_bfloat16* __restrict__ w3t, float* __restrict__ out,
    __hip_bfloat16* __restrict__ agg) {
    __shared__ __align__(16) char smem[38912];
    const int bid = blockIdx.x;
    const int t = threadIdx.x;

    if (bid < 1024) {
        float (*tile)[65] = (float (*)[65])smem;
        const int k0 = (bid >> 4) * 64;
        const int n0 = (bid & 15) * 64;
        const int c = t & 63, r0 = t >> 6;
#pragma unroll
        for (int i = 0; i < 16; i++) {
            int r = r0 + i * 4;
            tile[r][c] = w3[(size_t)(k0 + r) * H2 + n0 + c];
        }
        __syncthreads();
#pragma unroll
        for (int i = 0; i < 16; i++) {
            int nr = r0 + i * 4;
            w3t[(size_t)(n0 + nr) * KDIM + k0 + c] = __float2bfloat16(tile[c][nr]);
        }
        return;
    }
    if (bid < 1088) {
        out[(bid - 1024) * 256 + t] = b4[0];
        return;
    }

    const int sbid = bid - 1088;
    const int v = sbid >> 7;
    const int b0 = (sbid & 127) * 128;
    const int lane = t & 63, wv = t >> 6;
    const int l15 = lane & 15, g = lane >> 4;

    short* xsS   = (short*)smem;
    short* w1bhS = (short*)(smem + 10240);
    short* w1blS = (short*)(smem + 15360);
    short* Hs    = (short*)smem;
    short* w2bhS = (short*)(smem + 20480);
    short* w2blS = (short*)(smem + 29696);

    for (int c = t; c < 320; c += 256) {
        gload_lds16(w1bh_g + (size_t)v * 2560 + c * 8, (char*)w1bhS + c * 16);
        gload_lds16(w1bl_g + (size_t)v * 2560 + c * 8, (char*)w1blS + c * 16);
    }
    for (int c = t; c < 576; c += 256) {
        gload_lds16(w2bh_g + (size_t)v * 4608 + c * 8, (char*)w2bhS + c * 16);
        gload_lds16(w2bl_g + (size_t)v * 4608 + c * 8, (char*)w2blS + c * 16);
    }
#pragma unroll
    for (int i = 0; i < 2; i++) {
        int idx = t + i * 256;
        int row = idx >> 2, seg = idx & 3;
        float4 x4 = *(const float4*)(inputs + (size_t)(b0 + row) * (NVARS * LAG) + v * LAG + seg * 4);
        const float* xp = (const float*)&x4;
        short4v hv, lv;
#pragma unroll
        for (int j = 0; j < 4; j++) {
            short hi = f2bf_s(xp[j]);
            hv[j] = hi;
            lv[j] = f2bf_s(xp[j] - bf_s2f(hi));
        }
        *(short4v*)&xsS[row * 40 + seg * 4] = hv;
        *(short4v*)&xsS[row * 40 + 16 + seg * 4] = lv;
    }
    __syncthreads();

    short8 a1[2], b1hF[4], b1lF[4];
#pragma unroll
    for (int mt = 0; mt < 2; mt++)
        a1[mt] = *(const short8*)&xsS[(wv * 32 + mt * 16 + l15) * 40 + g * 8];
#pragma unroll
    for (int nt = 0; nt < 4; nt++) {
        b1hF[nt] = *(const short8*)&w1bhS[(nt * 16 + l15) * 40 + g * 8];
        b1lF[nt] = *(const short8*)&w1blS[(nt * 16 + l15) * 40 + g * 8];
    }
    f32x4 acc1[2][4];
#pragma unroll
    for (int mt = 0; mt < 2; mt++)
#pragma unroll
        for (int nt = 0; nt < 4; nt++) {
            acc1[mt][nt] = (f32x4){0.f, 0.f, 0.f, 0.f};
            acc1[mt][nt] = __builtin_amdgcn_mfma_f32_16x16x32_bf16(a1[mt], b1hF[nt], acc1[mt][nt], 0, 0, 0);
            acc1[mt][nt] = __builtin_amdgcn_mfma_f32_16x16x32_bf16(a1[mt], b1lF[nt], acc1[mt][nt], 0, 0, 0);
        }
    __syncthreads();

#pragma unroll
    for (int mt = 0; mt < 2; mt++)
#pragma unroll
        for (int nt = 0; nt < 4; nt++) {
            int col = nt * 16 + l15;
            float bias = b1g[v * H1 + col];
#pragma unroll
            for (int r = 0; r < 4; r++) {
                float h = fmaxf(acc1[mt][nt][r] + bias, 0.f);
                int row = wv * 32 + mt * 16 + g * 4 + r;
                Hs[row * 72 + col] = f2bf_s(h);
            }
        }
    __syncthreads();

    short8 a2[2][2], b2hF[4][2], b2lF[4][2];
#pragma unroll
    for (int mt = 0; mt < 2; mt++)
#pragma unroll
        for (int kc = 0; kc < 2; kc++)
            a2[mt][kc] = *(const short8*)&Hs[(wv * 32 + mt * 16 + l15) * 72 + kc * 32 + g * 8];
#pragma unroll
    for (int nt = 0; nt < 4; nt++)
#pragma unroll
        for (int kc = 0; kc < 2; kc++) {
            b2hF[nt][kc] = *(const short8*)&w2bhS[(nt * 16 + l15) * 72 + kc * 32 + g * 8];
            b2lF[nt][kc] = *(const short8*)&w2blS[(nt * 16 + l15) * 72 + kc * 32 + g * 8];
        }
    f32x4 acc2[2][4];
#pragma unroll
    for (int mt = 0; mt < 2; mt++)
#pragma unroll
        for (int nt = 0; nt < 4; nt++) {
            f32x4 a = (f32x4){0.f, 0.f, 0.f, 0.f};
            a = __builtin_amdgcn_mfma_f32_16x16x32_bf16(a2[mt][0], b2hF[nt][0], a, 0, 0, 0);
            a = __builtin_amdgcn_mfma_f32_16x16x32_bf16(a2[mt][1], b2hF[nt][1], a, 0, 0, 0);
            a = __builtin_amdgcn_mfma_f32_16x16x32_bf16(a2[mt][0], b2lF[nt][0], a, 0, 0, 0);
            a = __builtin_amdgcn_mfma_f32_16x16x32_bf16(a2[mt][1], b2lF[nt][1], a, 0, 0, 0);
            acc2[mt][nt] = a;
        }

    const float impv = impg[v];
#pragma unroll
    for (int mt = 0; mt < 2; mt++)
#pragma unroll
        for (int nt = 0; nt < 4; nt++) {
            int col = nt * 16 + l15;
            float bias = b2g[v * H1 + col];
#pragma unroll
            for (int r = 0; r < 4; r++) {
                float o = fmaxf(acc2[mt][nt][r] + bias, 0.f) * impv;
                int row = b0 + wv * 32 + mt * 16 + g * 4 + r;
                agg[(size_t)row * KDIM + v * H1 + col] = __float2bfloat16(o);
            }
        }
}

// ---------------------------------------------------------------------------
// Kernel 3: relu(agg @ W3 + b3) . W4 -> atomicAdd into out.
// r15: LDS-bytes/FLOP-optimized at constant TLP. ONE 1024-thread block per
// CU (grid 256, LDS 128 KB), 16 waves as 4x4, wave tile 64x64, tile 256^2.
// Frag reads per CU-K-tile: (4 wn + 4 wm) x 16 KB = 128 KB (r8: 192 KB) +
// 32 KB stage = 160 KB -> 1250-cyc LDS floor ~ 1242-cyc MFMA floor.
// TLP unchanged: 4 waves/SIMD (r8 had 2 blocks x 2/SIMD). Schedule is r8's
// proven single-barrier 4-buffer rotation; 2 stage-ops/tile -> vmcnt(4)
// certifies tile tt+1 (end-of-tile outstanding = tt+1..tt+3 = 6 ops).
// ---------------------------------------------------------------------------
#define NT 128   // K-tiles of 32

__global__ __launch_bounds__(1024, 4) void gemm3_kernel(
    const __hip_bfloat16* __restrict__ agg,   // [16384][4096]
    const __hip_bfloat16* __restrict__ w3t,   // [1024][4096]
    const float* __restrict__ b3, const float* __restrict__ W4,
    float* __restrict__ out) {
    const int bid = ((blockIdx.x & 7) << 5) + (blockIdx.x >> 3);   // T1 swizzle
    const int brow = (bid >> 2) * 256;
    const int bcol = (bid & 3) * 256;
    const int t = threadIdx.x;
    const int lane = t & 63;
    const int wid = t >> 6;                   // 16 waves
    const int wm = wid >> 2, wn = wid & 3;    // 4 x 4, wave tile 64x64
    const int l15 = lane & 15, g = lane >> 4;

    // LDS: buffer pair p (p=0..3) at p*32768: A 16 KB @ +0, B 16 KB @ +16384
    __shared__ __align__(16) char smem[131072];

    // staging: 1024 thr x 16B = one full 16-KB region per gload op.
    // dest linear, source col pre-swizzled (st_16x32, r8-proven).
    const int rA = t >> 2;
    const int colA = ((t & 3) * 8) ^ ((rA & 8) ? 16 : 0);
    const __hip_bfloat16* aS = agg + (size_t)(brow + rA) * KDIM + colA;
    const __hip_bfloat16* bS = w3t + (size_t)(bcol + rA) * KDIM + colA;

#define STAGE(p, kt) do { \
        gload_lds16(aS + (size_t)(kt) * 32, smem + (p) * 32768 + t * 16); \
        gload_lds16(bS + (size_t)(kt) * 32, smem + (p) * 32768 + 16384 + t * 16); } while (0)

    // swizzled fragment reads (row&8 == l15&8 for all m/n)
    const int coff = (g * 16) ^ ((l15 & 8) ? 32 : 0);
    const int aBase = (wm * 64 + l15) * 64 + coff;
    const int bBase = 16384 + (wn * 64 + l15) * 64 + coff;

#define LDA(i, p) fa[i] = *(const short8*)(smem + (p) * 32768 + aBase + (i) * 1024)
#define LDB(i, p) fb[i] = *(const short8*)(smem + (p) * 32768 + bBase + (i) * 1024)

    short8 fa[4], fb[4];
    f32x4 acc[4][4];
#pragma unroll
    for (int m = 0; m < 4; m++)
#pragma unroll
        for (int n = 0; n < 4; n++) acc[m][n] = (f32x4){0.f, 0.f, 0.f, 0.f};

#define TILE(p, DOSTAGE, kt3, VMSTR) do { \
        LDA(0, p); LDA(1, p); LDA(2, p); LDA(3, p); \
        LDB(0, p); LDB(1, p); LDB(2, p); LDB(3, p); \
        if (DOSTAGE) STAGE((kt3) & 3, kt3); \
        __builtin_amdgcn_s_setprio(1); \
        _Pragma("unroll") \
        for (int mm = 0; mm < 4; mm++) \
            _Pragma("unroll") \
            for (int nn = 0; nn < 4; nn++) \
                acc[mm][nn] = __builtin_amdgcn_mfma_f32_16x16x32_bf16( \
                    fa[mm], fb[nn], acc[mm][nn], 0, 0, 0); \
        __builtin_amdgcn_s_setprio(0); \
        asm volatile(VMSTR ::: "memory"); \
        __builtin_amdgcn_s_barrier(); \
        __builtin_amdgcn_sched_barrier(0); } while (0)

    // prologue: stage tiles 0,1,2 (6 ops); vmcnt(4) drains tile0; barrier.
    STAGE(0, 0);
    STAGE(1, 1);
    STAGE(2, 2);
    asm volatile("s_waitcnt vmcnt(4)" ::: "memory");
    __builtin_amdgcn_s_barrier();
    __builtin_amdgcn_sched_barrier(0);

    // main loop: tt = 0..123 (unroll 4 -> p compile-time), staging 3..127.
#pragma unroll 4
    for (int tt = 0; tt < NT - 4; ++tt) {
        TILE(tt & 3, 1, tt + 3, "s_waitcnt vmcnt(4)");
    }
    // tail: 124 (stages 127), 125, 126, 127
    TILE(0, 1, 127, "s_waitcnt vmcnt(4)");
    TILE(1, 0, 0,   "s_waitcnt vmcnt(2)");
    TILE(2, 0, 0,   "s_waitcnt vmcnt(0)");
    LDA(0, 3); LDA(1, 3); LDA(2, 3); LDA(3, 3);
    LDB(0, 3); LDB(1, 3); LDB(2, 3); LDB(3, 3);
    __builtin_amdgcn_s_setprio(1);
#pragma unroll
    for (int mm = 0; mm < 4; mm++)
#pragma unroll
        for (int nn = 0; nn < 4; nn++)
            acc[mm][nn] = __builtin_amdgcn_mfma_f32_16x16x32_bf16(
                fa[mm], fb[nn], acc[mm][nn], 0, 0, 0);
    __builtin_amdgcn_s_setprio(0);

    // epilogue: bias+relu, dot W4, 16-lane reduce, atomicAdd per row
    float bias[4], w4v[4];
#pragma unroll
    for (int n = 0; n < 4; n++) {
        int col = bcol + wn * 64 + n * 16 + l15;
        bias[n] = b3[col];
        w4v[n] = W4[col];
    }
#pragma unroll
    for (int m = 0; m < 4; m++) {
        float pr0 = 0.f, pr1 = 0.f, pr2 = 0.f, pr3 = 0.f;
#pragma unroll
        for (int n = 0; n < 4; n++) {
            pr0 += fmaxf(acc[m][n][0] + bias[n], 0.f) * w4v[n];
            pr1 += fmaxf(acc[m][n][1] + bias[n], 0.f) * w4v[n];
            pr2 += fmaxf(acc[m][n][2] + bias[n], 0.f) * w4v[n];
            pr3 += fmaxf(acc[m][n][3] + bias[n], 0.f) * w4v[n];
        }
#pragma unroll
        for (int mask = 1; mask < 16; mask <<= 1) {
            pr0 += __shfl_xor(pr0, mask, 64);
            pr1 += __shfl_xor(pr1, mask, 64);
            pr2 += __shfl_xor(pr2, mask, 64);
            pr3 += __shfl_xor(pr3, mask, 64);
        }
        if (l15 == 0) {
            int row = brow + wm * 64 + m * 16 + g * 4;
            atomicAdd(&out[row + 0], pr0);
            atomicAdd(&out[row + 1], pr1);
            atomicAdd(&out[row + 2], pr2);
            atomicAdd(&out[row + 3], pr3);
        }
    }
}

// ---------------------------------------------------------------------------
extern "C" void kernel_launch(void* const* d_in, const int* in_sizes, int n_in,
                              void* d_out, int out_size, void* d_ws, size_t ws_size,
                              hipStream_t stream) {
    const float* inputs = (const float*)d_in[0];
    const float* W1 = (const float*)d_in[1];
    const float* b1 = (const float*)d_in[2];
    const float* W2 = (const float*)d_in[3];
    const float* b2 = (const float*)d_in[4];
    const float* imp = (const float*)d_in[5];
    const float* W3 = (const float*)d_in[6];
    const float* b3 = (const float*)d_in[7];
    const float* W4 = (const float*)d_in[8];
    const float* b4 = (const float*)d_in[9];
    float* out = (float*)d_out;

    char* ws = (char*)d_ws;
    const size_t agg_bytes = (size_t)B_ROWS * KDIM * 2;        // 134 MB
    const size_t w3t_bytes = (size_t)H2 * KDIM * 2;            // 8.4 MB
    const size_t w1b_bytes = (size_t)NVARS * 64 * 40 * 2;
    const size_t w2b_bytes = (size_t)NVARS * 64 * 72 * 2;

    __hip_bfloat16* agg = (__hip_bfloat16*)ws;
    __hip_bfloat16* w3t = (__hip_bfloat16*)(ws + agg_bytes);
    short* w1bh = (short*)(ws + agg_bytes + w3t_bytes);
    short* w1bl = (short*)(ws + agg_bytes + w3t_bytes + w1b_bytes);
    short* w2bh = (short*)(ws + agg_bytes + w3t_bytes + 2 * w1b_bytes);
    short* w2bl = (short*)(ws + agg_bytes + w3t_bytes + 2 * w1b_bytes + w2b_bytes);

    hipLaunchKernelGGL(prep_w12_kernel, dim3(NVARS), dim3(256), 0, stream,
                       W1, W2, w1bh, w1bl, w2bh, w2bl);
    hipLaunchKernelGGL(subnets_fused_kernel, dim3(1088 + NVARS * (B_ROWS / 128)), dim3(256), 0, stream,
                       inputs, b1, b2, imp, w1bh, w1bl, w2bh, w2bl,
                       W3, b4, w3t, out, agg);
    hipLaunchKernelGGL(gemm3_kernel, dim3((B_ROWS / 256) * (H2 / 256)), dim3(1024), 0, stream,
                       agg, w3t, b3, W4, out);
}